// Round 1
// baseline (36.941 us; speedup 1.0000x reference)
//
#include <hip/hip_runtime.h>

#define NPTS 2048
#define NCP  32
#define P    4   // consecutive points per thread (float4 stores)
#define GB   4   // batches per block

// Binomial coefficients C(31, i) (exact)
static __device__ const float C31[NCP] = {
    1.f, 31.f, 465.f, 4495.f, 31465.f, 169911.f, 736281.f, 2629575.f,
    7888725.f, 20160075.f, 44352165.f, 84672315.f, 141120525.f, 206253075.f,
    265182525.f, 300540195.f, 300540195.f, 265182525.f, 206253075.f, 141120525.f,
    84672315.f, 44352165.f, 20160075.f, 7888725.f, 2629575.f, 736281.f,
    169911.f, 31465.f, 4495.f, 465.f, 31.f, 1.f
};

// Clamped knot vector value for knot index i (0..35): 4 zeros, interior
// (i-3)/29, 4 ones. Runtime-index version (constant-folded when i literal).
__device__ __forceinline__ float knq(int i) {
    int m = i - 3;
    m = m < 0 ? 0 : m;
    return (m >= 29) ? 1.0f : (float)m * (float)(1.0 / 29.0);
}

// Single fused kernel: block = 256 threads x {1024 consecutive points
// (4/thread), GB batches}. Both bases computed in registers:
//  - Bernstein deg-31 via exp2/log2 (no 32-reg power table, no underflow:
//    terms that truly underflow go to 0, endpoints exact via 1e-30 clamp)
//  - cubic B-spline 4-nonzero values via local de Boor recursion
// No workspace traffic, no global loads in the hot loop. All outputs
// written as float4 (1 KB contiguous per wave store).
__global__ void __launch_bounds__(256) fused_kernel(
    const float* __restrict__ bspline_cp, const float* __restrict__ nurbs_cp,
    const float* __restrict__ nurbs_w, const float* __restrict__ bezier_cp,
    float* __restrict__ out, int B) {
    const int tid = threadIdx.x;
    const int n0 = (blockIdx.x * 256 + tid) * P;   // first of this thread's 4 points
    const int b0 = blockIdx.y * GB;

    __shared__ float s_bs[GB * NCP * 2];
    __shared__ float s_nc[GB * NCP * 2];
    __shared__ float s_bz[GB * NCP * 2];
    __shared__ float s_w [GB * NCP];
    for (int idx = tid; idx < GB * NCP * 2; idx += 256) {
        s_bs[idx] = bspline_cp[(size_t)b0 * NCP * 2 + idx];
        s_nc[idx] = nurbs_cp[(size_t)b0 * NCP * 2 + idx];
        s_bz[idx] = bezier_cp[(size_t)b0 * NCP * 2 + idx];
    }
    for (int idx = tid; idx < GB * NCP; idx += 256)
        s_w[idx] = nurbs_w[(size_t)b0 * NCP + idx];
    __syncthreads();

    // Per-point parameter + Bernstein log-space params:
    // bern_i(t) = C31[i] * u^i * v^(31-i) = C31[i] * 2^(i*(lu-lv) + 31*lv)
    float tt[P], dd[P], e0[P];
#pragma unroll
    for (int p = 0; p < P; ++p) {
        int n = n0 + p;
        float t = (float)((double)n * (1.0 / (double)(NPTS - 1)));
        tt[p] = t;
        float lu = __builtin_amdgcn_logf(fmaxf(t, 1e-30f));
        float lv = __builtin_amdgcn_logf(fmaxf(1.0f - t, 1e-30f));
        dd[p] = lu - lv;
        e0[p] = 31.0f * lv;
    }

    const size_t cs = (size_t)B * 2 * NPTS;   // per-curve output stride

    // ---- Bezier: dense 32-term dot, basis generated in-register ----
    float4 ex[GB], ey[GB];
#pragma unroll
    for (int g = 0; g < GB; ++g) {
        ex[g] = make_float4(0.f, 0.f, 0.f, 0.f);
        ey[g] = make_float4(0.f, 0.f, 0.f, 0.f);
    }
#pragma unroll
    for (int i = 0; i < NCP; ++i) {
        const float fi = (float)i;
        const float c31 = C31[i];
        float4 br;
        br.x = c31 * __builtin_amdgcn_exp2f(fmaf(fi, dd[0], e0[0]));
        br.y = c31 * __builtin_amdgcn_exp2f(fmaf(fi, dd[1], e0[1]));
        br.z = c31 * __builtin_amdgcn_exp2f(fmaf(fi, dd[2], e0[2]));
        br.w = c31 * __builtin_amdgcn_exp2f(fmaf(fi, dd[3], e0[3]));
#pragma unroll
        for (int g = 0; g < GB; ++g) {
            float2 c = *reinterpret_cast<const float2*>(&s_bz[g * 64 + 2 * i]);
            ex[g].x = fmaf(br.x, c.x, ex[g].x);
            ex[g].y = fmaf(br.y, c.x, ex[g].y);
            ex[g].z = fmaf(br.z, c.x, ex[g].z);
            ex[g].w = fmaf(br.w, c.x, ex[g].w);
            ey[g].x = fmaf(br.x, c.y, ey[g].x);
            ey[g].y = fmaf(br.y, c.y, ey[g].y);
            ey[g].z = fmaf(br.z, c.y, ey[g].z);
            ey[g].w = fmaf(br.w, c.y, ey[g].w);
        }
    }
#pragma unroll
    for (int g = 0; g < GB; ++g) {
        const size_t base = 2 * cs + (size_t)(b0 + g) * 2 * NPTS + n0;
        *reinterpret_cast<float4*>(&out[base])        = ex[g];
        *reinterpret_cast<float4*>(&out[base + NPTS]) = ey[g];
    }

    // ---- Cubic B-spline basis: local de Boor (4 non-zero values/point) ----
    int   sp_[P];
    float bv[P][4];
#pragma unroll
    for (int p = 0; p < P; ++p) {
        const float t = tt[p];
        int s = (int)(t * 29.0f);
        s = s < 28 ? s : 28;
        sp_[p] = s;
        const int j = s + 3;             // knot-span index: U[j] <= t < U[j+1]
        const float L1 = t - knq(j);
        const float R1 = knq(j + 1) - t;
        const float L2 = t - knq(j - 1);
        const float R2 = knq(j + 2) - t;
        const float L3 = t - knq(j - 2);
        const float R3 = knq(j + 3) - t;
        float N0, N1, N2, N3, tmp, sv;
        // degree 1
        tmp = __builtin_amdgcn_rcpf(R1 + L1);
        N0 = R1 * tmp;
        N1 = L1 * tmp;
        // degree 2
        tmp = N0 * __builtin_amdgcn_rcpf(R1 + L2);
        N0 = R1 * tmp;
        sv = L2 * tmp;
        tmp = N1 * __builtin_amdgcn_rcpf(R2 + L1);
        N1 = fmaf(R2, tmp, sv);
        N2 = L1 * tmp;
        // degree 3
        tmp = N0 * __builtin_amdgcn_rcpf(R1 + L3);
        N0 = R1 * tmp;
        sv = L3 * tmp;
        tmp = N1 * __builtin_amdgcn_rcpf(R2 + L2);
        N1 = fmaf(R2, tmp, sv);
        sv = L2 * tmp;
        tmp = N2 * __builtin_amdgcn_rcpf(R3 + L1);
        N2 = fmaf(R3, tmp, sv);
        N3 = L1 * tmp;
        bv[p][0] = N0; bv[p][1] = N1; bv[p][2] = N2; bv[p][3] = N3;
    }

    // ---- B-spline + NURBS: sparse 4-term span dots ----
#pragma unroll
    for (int g = 0; g < GB; ++g) {
        float4 bx, by, nx, ny;
        float* bxp = &bx.x; float* byp = &by.x;
        float* nxp = &nx.x; float* nyp = &ny.x;
#pragma unroll
        for (int p = 0; p < P; ++p) {
            float sbx = 0.f, sby = 0.f, snx = 0.f, sny = 0.f, den = 0.f;
#pragma unroll
            for (int k = 0; k < 4; ++k) {
                int idx = sp_[p] + k;
                float c = bv[p][k];
                float2 cb = *reinterpret_cast<const float2*>(&s_bs[g * 64 + idx * 2]);
                sbx = fmaf(c, cb.x, sbx); sby = fmaf(c, cb.y, sby);
                float wb = c * s_w[g * 32 + idx];
                den += wb;
                float2 cn = *reinterpret_cast<const float2*>(&s_nc[g * 64 + idx * 2]);
                snx = fmaf(wb, cn.x, snx); sny = fmaf(wb, cn.y, sny);
            }
            float inv = 1.0f / (den + 1e-8f);
            bxp[p] = sbx; byp[p] = sby;
            nxp[p] = snx * inv; nyp[p] = sny * inv;
        }
        const size_t base = (size_t)(b0 + g) * 2 * NPTS + n0;
        *reinterpret_cast<float4*>(&out[base])             = bx;
        *reinterpret_cast<float4*>(&out[base + NPTS])      = by;
        *reinterpret_cast<float4*>(&out[cs + base])        = nx;
        *reinterpret_cast<float4*>(&out[cs + base + NPTS]) = ny;
    }
}

extern "C" void kernel_launch(void* const* d_in, const int* in_sizes, int n_in,
                              void* d_out, int out_size, void* d_ws, size_t ws_size,
                              hipStream_t stream) {
    const float* bspline_cp = (const float*)d_in[0];
    const float* nurbs_cp   = (const float*)d_in[1];
    const float* nurbs_w    = (const float*)d_in[2];
    const float* bezier_cp  = (const float*)d_in[3];
    float* out = (float*)d_out;

    const int B = in_sizes[2] / NCP;              // 2048

    hipLaunchKernelGGL(fused_kernel, dim3(NPTS / (256 * P), B / GB), dim3(256), 0, stream,
                       bspline_cp, nurbs_cp, nurbs_w, bezier_cp, out, B);
}

// Round 2
// 26.933 us; speedup vs baseline: 1.3716x; 1.3716x over previous
//
#include <hip/hip_runtime.h>

#define NPTS 2048
#define NCP  32
#define GB   4   // batches per block

// Binomial coefficients C(31, i) (exact)
static __device__ const float C31[NCP] = {
    1.f, 31.f, 465.f, 4495.f, 31465.f, 169911.f, 736281.f, 2629575.f,
    7888725.f, 20160075.f, 44352165.f, 84672315.f, 141120525.f, 206253075.f,
    265182525.f, 300540195.f, 300540195.f, 265182525.f, 206253075.f, 141120525.f,
    84672315.f, 44352165.f, 20160075.f, 7888725.f, 2629575.f, 736281.f,
    169911.f, 31465.f, 4495.f, 465.f, 31.f, 1.f
};

// Clamped knot vector value for knot index i (0..35): 4 zeros, interior
// (i-3)/29, 4 ones.
__device__ __forceinline__ float knq(int i) {
    int m = i - 3;
    m = m < 0 ? 0 : m;
    return (m >= 29) ? 1.0f : (float)m * (float)(1.0 / 29.0);
}

// One point per thread, GB batches per block. All per-thread state scalar so
// VGPR <= 64 -> 8 waves/SIMD (launch_bounds(256,8)). Grid 8x512 = 4096 blocks
// = 16 blocks/CU: latency-hiding via occupancy instead of per-thread ILP.
__global__ void __launch_bounds__(256, 8) fused_kernel(
    const float* __restrict__ bspline_cp, const float* __restrict__ nurbs_cp,
    const float* __restrict__ nurbs_w, const float* __restrict__ bezier_cp,
    float* __restrict__ out, int B) {
    const int tid = threadIdx.x;
    const int n   = blockIdx.x * 256 + tid;   // this thread's point
    const int b0  = blockIdx.y * GB;

    __shared__ float s_bs[GB * NCP * 2];
    __shared__ float s_nc[GB * NCP * 2];
    __shared__ float s_bz[GB * NCP * 2];
    __shared__ float s_w [GB * NCP];
    for (int idx = tid; idx < GB * NCP * 2; idx += 256) {
        s_bs[idx] = bspline_cp[(size_t)b0 * NCP * 2 + idx];
        s_nc[idx] = nurbs_cp[(size_t)b0 * NCP * 2 + idx];
        s_bz[idx] = bezier_cp[(size_t)b0 * NCP * 2 + idx];
    }
    for (int idx = tid; idx < GB * NCP; idx += 256)
        s_w[idx] = nurbs_w[(size_t)b0 * NCP + idx];
    __syncthreads();

    const float t = (float)((double)n * (1.0 / (double)(NPTS - 1)));
    // Bernstein in log2 space: bern_i = C31[i] * 2^(i*(lu-lv) + 31*lv)
    const float lu = __builtin_amdgcn_logf(fmaxf(t, 1e-30f));
    const float lv = __builtin_amdgcn_logf(fmaxf(1.0f - t, 1e-30f));
    const float dd = lu - lv;
    const float e0 = 31.0f * lv;

    const size_t cs = (size_t)B * 2 * NPTS;   // per-curve output stride

    // ---- Bezier: dense 32-term dot, basis generated in-register ----
    float ex[GB], ey[GB];
#pragma unroll
    for (int g = 0; g < GB; ++g) { ex[g] = 0.f; ey[g] = 0.f; }
#pragma unroll
    for (int i = 0; i < NCP; i += 2) {
        const float ba = C31[i]     * __builtin_amdgcn_exp2f(fmaf((float)i,       dd, e0));
        const float bb = C31[i + 1] * __builtin_amdgcn_exp2f(fmaf((float)(i + 1), dd, e0));
#pragma unroll
        for (int g = 0; g < GB; ++g) {
            // 16B-aligned: byte offset = 256*g + 8*i, i even
            float4 c = *reinterpret_cast<const float4*>(&s_bz[g * 64 + 2 * i]);
            ex[g] = fmaf(ba, c.x, fmaf(bb, c.z, ex[g]));
            ey[g] = fmaf(ba, c.y, fmaf(bb, c.w, ey[g]));
        }
    }
#pragma unroll
    for (int g = 0; g < GB; ++g) {
        const size_t base = 2 * cs + (size_t)(b0 + g) * 2 * NPTS + n;
        out[base]        = ex[g];
        out[base + NPTS] = ey[g];
    }

    // ---- Cubic B-spline basis: local de Boor (4 non-zero values) ----
    int s = (int)(t * 29.0f);
    s = s < 28 ? s : 28;
    const int j = s + 3;                 // knot-span: U[j] <= t < U[j+1]
    const float L1 = t - knq(j);
    const float R1 = knq(j + 1) - t;
    const float L2 = t - knq(j - 1);
    const float R2 = knq(j + 2) - t;
    const float L3 = t - knq(j - 2);
    const float R3 = knq(j + 3) - t;
    float N0, N1, N2, N3, tmp, sv;
    tmp = __builtin_amdgcn_rcpf(R1 + L1);
    N0 = R1 * tmp;
    N1 = L1 * tmp;
    tmp = N0 * __builtin_amdgcn_rcpf(R1 + L2);
    N0 = R1 * tmp;
    sv = L2 * tmp;
    tmp = N1 * __builtin_amdgcn_rcpf(R2 + L1);
    N1 = fmaf(R2, tmp, sv);
    N2 = L1 * tmp;
    tmp = N0 * __builtin_amdgcn_rcpf(R1 + L3);
    N0 = R1 * tmp;
    sv = L3 * tmp;
    tmp = N1 * __builtin_amdgcn_rcpf(R2 + L2);
    N1 = fmaf(R2, tmp, sv);
    sv = L2 * tmp;
    tmp = N2 * __builtin_amdgcn_rcpf(R3 + L1);
    N2 = fmaf(R3, tmp, sv);
    N3 = L1 * tmp;

    // ---- B-spline + NURBS: sparse 4-term span dots ----
#pragma unroll
    for (int g = 0; g < GB; ++g) {
        float sbx = 0.f, sby = 0.f, snx = 0.f, sny = 0.f, den = 0.f;
#pragma unroll
        for (int k = 0; k < 4; ++k) {
            const int idx = s + k;
            const float c = (k == 0) ? N0 : (k == 1) ? N1 : (k == 2) ? N2 : N3;
            float2 cb = *reinterpret_cast<const float2*>(&s_bs[g * 64 + idx * 2]);
            sbx = fmaf(c, cb.x, sbx); sby = fmaf(c, cb.y, sby);
            const float wb = c * s_w[g * 32 + idx];
            den += wb;
            float2 cn = *reinterpret_cast<const float2*>(&s_nc[g * 64 + idx * 2]);
            snx = fmaf(wb, cn.x, snx); sny = fmaf(wb, cn.y, sny);
        }
        const float inv = __builtin_amdgcn_rcpf(den + 1e-8f);
        const size_t base = (size_t)(b0 + g) * 2 * NPTS + n;
        out[base]                  = sbx;
        out[base + NPTS]           = sby;
        out[cs + base]             = snx * inv;
        out[cs + base + NPTS]      = sny * inv;
    }
}

extern "C" void kernel_launch(void* const* d_in, const int* in_sizes, int n_in,
                              void* d_out, int out_size, void* d_ws, size_t ws_size,
                              hipStream_t stream) {
    const float* bspline_cp = (const float*)d_in[0];
    const float* nurbs_cp   = (const float*)d_in[1];
    const float* nurbs_w    = (const float*)d_in[2];
    const float* bezier_cp  = (const float*)d_in[3];
    float* out = (float*)d_out;

    const int B = in_sizes[2] / NCP;              // 2048

    hipLaunchKernelGGL(fused_kernel, dim3(NPTS / 256, B / GB), dim3(256), 0, stream,
                       bspline_cp, nurbs_cp, nurbs_w, bezier_cp, out, B);
}